// Round 1
// baseline (652.067 us; speedup 1.0000x reference)
//
#include <hip/hip_runtime.h>

typedef __attribute__((ext_vector_type(8))) short bf16x8;
typedef __attribute__((ext_vector_type(4))) float f32x4;

#define DEVFN __device__ __forceinline__

DEVFN short f2bf(float f) {
    union { float f; unsigned u; } v; v.f = f;
    unsigned r = (v.u + 0x7FFFu + ((v.u >> 16) & 1u)) >> 16;
    return (short)(unsigned short)r;
}
DEVFN float bf2f(short h) {
    union { unsigned u; float f; } v; v.u = ((unsigned)(unsigned short)h) << 16;
    return v.f;
}

// ---------------- prep kernels ----------------

// W1p[i][j] = sum_m Wb[i][m] * We1[128+m][j]   (i<200); block 200 builds b1p
__global__ __launch_bounds__(128) void build_w1p_k(
    const float* __restrict__ Wb, const float* __restrict__ We1,
    const float* __restrict__ bb, const float* __restrict__ be1,
    float* __restrict__ W1p, float* __restrict__ b1p)
{
    int j = threadIdx.x;
    const float* B = We1 + 128 * 128;
    int i = blockIdx.x;
    if (i < 200) {
        float a = 0.f;
        for (int m = 0; m < 128; m++) a += Wb[i * 128 + m] * B[m * 128 + j];
        W1p[i * 128 + j] = a;
    } else {
        float a = be1[j];
        for (int m = 0; m < 128; m++) a += bb[m] * B[m * 128 + j];
        b1p[j] = a;
    }
}

// tab[c][i][j] = (c==0? b1p[j]:0) + sum_k exp(-1250*(t-k/49)^2) * W1p[c*50+k][j]
__global__ __launch_bounds__(128) void build_tab_k(
    const float* __restrict__ W1p, const float* __restrict__ b1p,
    short* __restrict__ tab)
{
    int i = blockIdx.x;   // 0..1024
    int c = blockIdx.y;   // 0..3
    int j = threadIdx.x;
    float t = (float)i * (1.0f / 1024.0f);
    float acc = (c == 0) ? b1p[j] : 0.f;
    int kc = (int)(t * 49.f + 0.5f);
    for (int dk = -6; dk <= 6; dk++) {
        int k = kc + dk;
        if (k >= 0 && k < 50) {
            float d = t - (float)k * (1.f / 49.f);
            float g = expf(-1250.f * d * d);
            acc += g * W1p[(c * 50 + k) * 128 + j];
        }
    }
    tab[((size_t)(c * 1025 + i)) * 128 + j] = f2bf(acc);
}

// Build MFMA-fragment-layout bf16 B' = diag(s) @ W, bias' = bias + t @ W.
// s,t from BN stats (16 replicas of [sum[128], sumsq[128]]); statsG==null -> s=1,t=0
__global__ __launch_bounds__(256) void fold_k(
    const float* __restrict__ W, const float* __restrict__ bias,
    const float* __restrict__ statsG, const float* __restrict__ gamma,
    const float* __restrict__ beta, float invNs,
    short* __restrict__ Bp, float* __restrict__ biasOut)
{
    __shared__ float sS[128], sT[128];
    int tid = threadIdx.x;
    if (tid < 128) {
        float s = 1.f, t = 0.f;
        if (statsG) {
            float sum = 0.f, sq = 0.f;
            for (int r = 0; r < 16; r++) {
                sum += statsG[r * 256 + tid];
                sq  += statsG[r * 256 + 128 + tid];
            }
            float m = sum * invNs;
            float var = sq * invNs - m * m;
            float rs = rsqrtf(var + 1e-5f);
            s = rs * gamma[tid];
            t = beta[tid] - m * s;
        }
        sS[tid] = s; sT[tid] = t;
    }
    __syncthreads();
    if (tid < 128) {
        float b = bias ? bias[tid] : 0.f;
        if (statsG) for (int k = 0; k < 128; k++) b += sT[k] * W[k * 128 + tid];
        biasOut[tid] = b;
    }
    // frag layout: Bp[((n*4+ks)*64+lane)*8 + i] = bf16( s[k]*W[k][col] ),
    //   k = ks*32 + (lane>>4)*8 + i,  col = n*16 + (lane&15)
    for (int idx = tid; idx < 2048; idx += 256) {
        int n = idx >> 8;
        int ks = (idx >> 6) & 3;
        int lane = idx & 63;
        int k8 = ks * 32 + (lane >> 4) * 8;
        int col = n * 16 + (lane & 15);
        bf16x8 fv;
        #pragma unroll
        for (int i2 = 0; i2 < 8; i2++)
            fv[i2] = f2bf(sS[k8 + i2] * W[(k8 + i2) * 128 + col]);
        *(bf16x8*)(Bp + (size_t)idx * 8) = fv;
    }
}

// ---------------- edge pass 1: z1 = lrelu(xs1[src]+xt1[dst]+tab lerps) ----------------
__global__ __launch_bounds__(256) void edge_z1_k(
    const short* __restrict__ xs1b, const short* __restrict__ xt1b,
    const short* __restrict__ tab, const float* __restrict__ ea,
    const int* __restrict__ srcI, const int* __restrict__ dstI,
    short* __restrict__ z1, float* __restrict__ stats, int Etot)
{
    int tid = threadIdx.x;
    int j = tid & 127, hh = tid >> 7;
    int e0 = blockIdx.x * 256;
    float sum = 0.f, sq = 0.f;
    for (int el = hh; el < 256; el += 2) {
        int e = e0 + el;
        if (e < Etot) {
            int s = srcI[e], d = dstI[e];
            float pre = bf2f(xs1b[(size_t)s * 128 + j]) + bf2f(xt1b[(size_t)d * 128 + j]);
            #pragma unroll
            for (int c = 0; c < 4; c++) {
                float t = ea[(size_t)e * 4 + c];
                float u = t * 1024.f;
                int i0 = (int)u;
                if (i0 > 1023) i0 = 1023;
                if (i0 < 0) i0 = 0;
                float f = u - (float)i0;
                const short* tb = tab + ((size_t)(c * 1025 + i0)) * 128 + j;
                float v0 = bf2f(tb[0]), v1 = bf2f(tb[128]);
                pre += v0 + f * (v1 - v0);
            }
            float z = pre >= 0.f ? pre : 0.01f * pre;
            z1[(size_t)e * 128 + j] = f2bf(z);
            sum += z; sq += z * z;
        }
    }
    __shared__ float lS[256], lQ[256];
    lS[tid] = sum; lQ[tid] = sq;
    __syncthreads();
    if (tid < 128) {
        float s2 = lS[tid] + lS[tid + 128];
        float q2 = lQ[tid] + lQ[tid + 128];
        int rep = blockIdx.x & 15;
        atomicAdd(&stats[rep * 256 + tid], s2);
        atomicAdd(&stats[rep * 256 + 128 + tid], q2);
    }
}

// ---------------- generic tall-skinny MFMA GEMM: out = A(Mx128) @ B'(128x128) ----------------
// EPI 0: out fp32 (xd) + zacc = v*val     (AMODE 0)
// EPI 1: out bf16                          (AMODE 0)
// EPI 2: z=lrelu(val); out bf16; BN stats  (AMODE 0/1)
// EPI 3: scatter: atomicAdd(zacc[dst], coeff*val*xd[src])  (AMODE 1)
// EPI 4: out fp32 = val + xres             (AMODE 1)
template<int AMODE, int EPI>
__global__ __launch_bounds__(256) void gemm_k(
    const void* __restrict__ A, int M,
    const short* __restrict__ Bp, const float* __restrict__ bias,
    void* __restrict__ out, float* __restrict__ stats,
    const float* __restrict__ xd, float* __restrict__ zacc,
    const float* __restrict__ ea, const int* __restrict__ srcI,
    const int* __restrict__ dstI, const float* __restrict__ vvec,
    const float* __restrict__ xres)
{
    __shared__ __align__(16) short ldsB[16384];
    __shared__ float ldsS[128], ldsQ[128];
    int tid = threadIdx.x;
    {
        const float4* s4 = (const float4*)Bp;
        float4* d4 = (float4*)ldsB;
        #pragma unroll
        for (int i = 0; i < 8; i++) d4[tid + i * 256] = s4[tid + i * 256];
    }
    if (EPI == 2) { if (tid < 128) { ldsS[tid] = 0.f; ldsQ[tid] = 0.f; } }
    __syncthreads();

    int wave = tid >> 6, lane = tid & 63;
    int kgrp = lane >> 4;
    int colbase = lane & 15;
    int rowA = blockIdx.x * 64 + wave * 16 + colbase;
    bool rvalid = rowA < M;

    f32x4 acc[8];
    #pragma unroll
    for (int n = 0; n < 8; n++) acc[n] = (f32x4){0.f, 0.f, 0.f, 0.f};

    #pragma unroll
    for (int ks = 0; ks < 4; ks++) {
        bf16x8 af = (bf16x8){0, 0, 0, 0, 0, 0, 0, 0};
        if (rvalid) {
            if (AMODE == 1) {
                af = *(const bf16x8*)((const short*)A + (size_t)rowA * 128 + ks * 32 + kgrp * 8);
            } else {
                const float* ap = (const float*)A + (size_t)rowA * 128 + ks * 32 + kgrp * 8;
                float4 f0 = ((const float4*)ap)[0];
                float4 f1 = ((const float4*)ap)[1];
                af[0] = f2bf(f0.x); af[1] = f2bf(f0.y); af[2] = f2bf(f0.z); af[3] = f2bf(f0.w);
                af[4] = f2bf(f1.x); af[5] = f2bf(f1.y); af[6] = f2bf(f1.z); af[7] = f2bf(f1.w);
            }
        }
        #pragma unroll
        for (int n = 0; n < 8; n++) {
            bf16x8 bf = *(const bf16x8*)(ldsB + ((size_t)((n * 4 + ks) * 64 + lane)) * 8);
            acc[n] = __builtin_amdgcn_mfma_f32_16x16x32_bf16(af, bf, acc[n], 0, 0, 0);
        }
    }

    int rbase = blockIdx.x * 64 + wave * 16 + kgrp * 4;
    float bcol[8];
    #pragma unroll
    for (int n = 0; n < 8; n++) bcol[n] = bias ? bias[n * 16 + colbase] : 0.f;

    if (EPI == 0) {
        float* outf = (float*)out;
        #pragma unroll
        for (int n = 0; n < 8; n++) {
            int col = n * 16 + colbase;
            float vc = vvec[col];
            #pragma unroll
            for (int r = 0; r < 4; r++) {
                int row = rbase + r;
                if (row < M) {
                    float val = acc[n][r] + bcol[n];
                    outf[(size_t)row * 128 + col] = val;
                    zacc[(size_t)row * 128 + col] = vc * val;
                }
            }
        }
    } else if (EPI == 1) {
        short* outh = (short*)out;
        #pragma unroll
        for (int n = 0; n < 8; n++) {
            int col = n * 16 + colbase;
            #pragma unroll
            for (int r = 0; r < 4; r++) {
                int row = rbase + r;
                if (row < M) outh[(size_t)row * 128 + col] = f2bf(acc[n][r] + bcol[n]);
            }
        }
    } else if (EPI == 2) {
        short* outh = (short*)out;
        #pragma unroll
        for (int n = 0; n < 8; n++) {
            int col = n * 16 + colbase;
            float s4 = 0.f, q4 = 0.f;
            #pragma unroll
            for (int r = 0; r < 4; r++) {
                int row = rbase + r;
                if (row < M) {
                    float z = acc[n][r] + bcol[n];
                    z = z >= 0.f ? z : 0.01f * z;
                    outh[(size_t)row * 128 + col] = f2bf(z);
                    s4 += z; q4 += z * z;
                }
            }
            atomicAdd(&ldsS[col], s4);
            atomicAdd(&ldsQ[col], q4);
        }
        __syncthreads();
        if (tid < 128) {
            int rep = blockIdx.x & 15;
            atomicAdd(&stats[rep * 256 + tid], ldsS[tid]);
            atomicAdd(&stats[rep * 256 + 128 + tid], ldsQ[tid]);
        }
    } else if (EPI == 3) {
        int sx[4], dx[4]; float cf[4]; bool ok[4];
        #pragma unroll
        for (int r = 0; r < 4; r++) {
            int row = rbase + r;
            ok[r] = row < M;
            if (ok[r]) {
                sx[r] = srcI[row]; dx[r] = dstI[row];
                cf[r] = cosf(1.57079632679f * ea[(size_t)row * 4 + 3]);
            } else { sx[r] = 0; dx[r] = 0; cf[r] = 0.f; }
        }
        #pragma unroll
        for (int n = 0; n < 8; n++) {
            int col = n * 16 + colbase;
            #pragma unroll
            for (int r = 0; r < 4; r++) {
                if (ok[r]) {
                    float val = acc[n][r] + bcol[n];
                    float mm = cf[r] * val * xd[(size_t)sx[r] * 128 + col];
                    atomicAdd(&zacc[(size_t)dx[r] * 128 + col], mm);
                }
            }
        }
    } else if (EPI == 4) {
        float* outf = (float*)out;
        #pragma unroll
        for (int n = 0; n < 8; n++) {
            int col = n * 16 + colbase;
            #pragma unroll
            for (int r = 0; r < 4; r++) {
                int row = rbase + r;
                if (row < M)
                    outf[(size_t)row * 128 + col] = acc[n][r] + bcol[n] + xres[(size_t)row * 128 + col];
            }
        }
    }
}

extern "C" void kernel_launch(void* const* d_in, const int* in_sizes, int n_in,
                              void* d_out, int out_size, void* d_ws, size_t ws_size,
                              hipStream_t stream)
{
    const float* x    = (const float*)d_in[0];
    const float* ea   = (const float*)d_in[1];
    const int*   eidx = (const int*)d_in[2];
    const float* Wb   = (const float*)d_in[3];
    const float* bb   = (const float*)d_in[4];
    const float* We1  = (const float*)d_in[5];
    const float* be1  = (const float*)d_in[6];
    const float* ge1  = (const float*)d_in[7];
    const float* bte1 = (const float*)d_in[8];
    const float* We2  = (const float*)d_in[9];
    const float* be2  = (const float*)d_in[10];
    const float* ge2  = (const float*)d_in[11];
    const float* bte2 = (const float*)d_in[12];
    const float* We3  = (const float*)d_in[13];
    const float* be3  = (const float*)d_in[14];
    const float* Wd   = (const float*)d_in[15];
    const float* bd   = (const float*)d_in[16];
    const float* vv   = (const float*)d_in[17];
    const float* Wn1  = (const float*)d_in[18];
    const float* bn1  = (const float*)d_in[19];
    const float* gn   = (const float*)d_in[20];
    const float* btn  = (const float*)d_in[21];
    const float* Wn2  = (const float*)d_in[22];
    const float* bn2  = (const float*)d_in[23];

    const int NN = in_sizes[0] / 128;   // 50000
    const int EE = in_sizes[1] / 4;     // 300000

    char* ws = (char*)d_ws;
    size_t oEZ   = 0;
    size_t oXD   = oEZ   + (size_t)EE * 128 * 2;
    size_t oXS   = oXD   + (size_t)NN * 128 * 4;
    size_t oXT   = oXS   + (size_t)NN * 128 * 2;
    size_t oZACC = oXT   + (size_t)NN * 128 * 2;
    size_t oZN   = oZACC + (size_t)NN * 128 * 4;
    size_t oTAB  = oZN   + (size_t)NN * 128 * 2;
    size_t oW1P  = oTAB  + (size_t)4 * 1025 * 128 * 2;
    size_t oB1P  = oW1P  + (size_t)200 * 128 * 4;
    size_t oBP   = oB1P  + 512;
    size_t oBIAS = oBP   + (size_t)7 * 32768;
    size_t oST   = oBIAS + (size_t)7 * 512;

    short* eZ   = (short*)(ws + oEZ);
    float* xd   = (float*)(ws + oXD);
    short* xs1b = (short*)(ws + oXS);
    short* xt1b = (short*)(ws + oXT);
    float* zacc = (float*)(ws + oZACC);
    short* zn   = (short*)(ws + oZN);
    short* tab  = (short*)(ws + oTAB);
    float* W1p  = (float*)(ws + oW1P);
    float* b1p  = (float*)(ws + oB1P);
    short* bp   = (short*)(ws + oBP);
    short* BpWd = bp + 0 * 16384;
    short* BpXs = bp + 1 * 16384;
    short* BpXt = bp + 2 * 16384;
    short* BpW2 = bp + 3 * 16384;
    short* BpW3 = bp + 4 * 16384;
    short* BpN1 = bp + 5 * 16384;
    short* BpN2 = bp + 6 * 16384;
    float* bo   = (float*)(ws + oBIAS);
    float* b2p  = bo + 0 * 128;
    float* b3p  = bo + 1 * 128;
    float* b2np = bo + 2 * 128;
    float* bdum = bo + 3 * 128;
    float* st1  = (float*)(ws + oST);
    float* st2  = st1 + 4096;
    float* stN  = st1 + 8192;

    hipMemsetAsync(st1, 0, 3 * 16384, stream);

    build_w1p_k<<<201, 128, 0, stream>>>(Wb, We1, bb, be1, W1p, b1p);
    build_tab_k<<<dim3(1025, 4), 128, 0, stream>>>(W1p, b1p, tab);

    fold_k<<<1, 256, 0, stream>>>(Wd, nullptr, nullptr, nullptr, nullptr, 0.f, BpWd, bdum);
    fold_k<<<1, 256, 0, stream>>>(We1, nullptr, nullptr, nullptr, nullptr, 0.f, BpXs, bdum);
    fold_k<<<1, 256, 0, stream>>>(We1 + 256 * 128, nullptr, nullptr, nullptr, nullptr, 0.f, BpXt, bdum);
    fold_k<<<1, 256, 0, stream>>>(Wn1, nullptr, nullptr, nullptr, nullptr, 0.f, BpN1, bdum);

    int gN = (NN + 63) / 64;
    int gE = (EE + 63) / 64;
    // node precompute: xd = x@Wd+bd (+ zacc = v*xd), xs1 = x@We1_top, xt1 = x@We1_bot
    gemm_k<0, 0><<<gN, 256, 0, stream>>>(x, NN, BpWd, bd, xd, nullptr, nullptr, zacc,
                                         nullptr, nullptr, nullptr, vv, nullptr);
    gemm_k<0, 1><<<gN, 256, 0, stream>>>(x, NN, BpXs, nullptr, xs1b, nullptr, nullptr, nullptr,
                                         nullptr, nullptr, nullptr, nullptr, nullptr);
    gemm_k<0, 1><<<gN, 256, 0, stream>>>(x, NN, BpXt, nullptr, xt1b, nullptr, nullptr, nullptr,
                                         nullptr, nullptr, nullptr, nullptr, nullptr);

    edge_z1_k<<<(EE + 255) / 256, 256, 0, stream>>>(xs1b, xt1b, tab, ea, eidx, eidx + EE,
                                                    eZ, st1, EE);

    fold_k<<<1, 256, 0, stream>>>(We2, be2, st1, ge1, bte1, 1.f / (float)EE, BpW2, b2p);
    gemm_k<1, 2><<<gE, 256, 0, stream>>>(eZ, EE, BpW2, b2p, eZ, st2, nullptr, nullptr,
                                         nullptr, nullptr, nullptr, nullptr, nullptr);

    fold_k<<<1, 256, 0, stream>>>(We3, be3, st2, ge2, bte2, 1.f / (float)EE, BpW3, b3p);
    gemm_k<1, 3><<<gE, 256, 0, stream>>>(eZ, EE, BpW3, b3p, nullptr, nullptr, xd, zacc,
                                         ea, eidx, eidx + EE, nullptr, nullptr);

    gemm_k<0, 2><<<gN, 256, 0, stream>>>(zacc, NN, BpN1, bn1, zn, stN, nullptr, nullptr,
                                         nullptr, nullptr, nullptr, nullptr, nullptr);

    fold_k<<<1, 256, 0, stream>>>(Wn2, bn2, stN, gn, btn, 1.f / (float)NN, BpN2, b2np);
    gemm_k<1, 4><<<gN, 256, 0, stream>>>(zn, NN, BpN2, b2np, d_out, nullptr, nullptr, nullptr,
                                         nullptr, nullptr, nullptr, nullptr, x);
}

// Round 2
// 604.343 us; speedup vs baseline: 1.0790x; 1.0790x over previous
//
#include <hip/hip_runtime.h>

typedef __attribute__((ext_vector_type(8))) short bf16x8;
typedef __attribute__((ext_vector_type(4))) float f32x4;

#define DEVFN __device__ __forceinline__

DEVFN short f2bf(float f) {
    union { float f; unsigned u; } v; v.f = f;
    unsigned r = (v.u + 0x7FFFu + ((v.u >> 16) & 1u)) >> 16;
    return (short)(unsigned short)r;
}
DEVFN float bf2f(short h) {
    union { unsigned u; float f; } v; v.u = ((unsigned)(unsigned short)h) << 16;
    return v.f;
}

// ---------------- prep kernels ----------------

// W1p[i][j] = sum_m Wb[i][m] * We1[128+m][j]   (i<200); block 200 builds b1p
__global__ __launch_bounds__(128) void build_w1p_k(
    const float* __restrict__ Wb, const float* __restrict__ We1,
    const float* __restrict__ bb, const float* __restrict__ be1,
    float* __restrict__ W1p, float* __restrict__ b1p)
{
    int j = threadIdx.x;
    const float* B = We1 + 128 * 128;
    int i = blockIdx.x;
    if (i < 200) {
        float a = 0.f;
        for (int m = 0; m < 128; m++) a += Wb[i * 128 + m] * B[m * 128 + j];
        W1p[i * 128 + j] = a;
    } else {
        float a = be1[j];
        for (int m = 0; m < 128; m++) a += bb[m] * B[m * 128 + j];
        b1p[j] = a;
    }
}

// tab[c][i][j] = (c==0? b1p[j]:0) + sum_k exp(-1250*(t-k/49)^2) * W1p[c*50+k][j]
__global__ __launch_bounds__(128) void build_tab_k(
    const float* __restrict__ W1p, const float* __restrict__ b1p,
    short* __restrict__ tab)
{
    int i = blockIdx.x;   // 0..1024
    int c = blockIdx.y;   // 0..3
    int j = threadIdx.x;
    float t = (float)i * (1.0f / 1024.0f);
    float acc = (c == 0) ? b1p[j] : 0.f;
    int kc = (int)(t * 49.f + 0.5f);
    for (int dk = -6; dk <= 6; dk++) {
        int k = kc + dk;
        if (k >= 0 && k < 50) {
            float d = t - (float)k * (1.f / 49.f);
            float g = expf(-1250.f * d * d);
            acc += g * W1p[(c * 50 + k) * 128 + j];
        }
    }
    tab[((size_t)(c * 1025 + i)) * 128 + j] = f2bf(acc);
}

// Plain repack of 4 weight mats into MFMA B-fragment layout (no BN fold).
// frag layout: Bp[idx*8+i] with idx=(n*4+ks)*64+lane, k=ks*32+(lane>>4)*8+i, col=n*16+(lane&15)
__global__ __launch_bounds__(256) void fold_plain_k(
    const float* __restrict__ W0, const float* __restrict__ W1,
    const float* __restrict__ W2, const float* __restrict__ W3,
    short* __restrict__ O0, short* __restrict__ O1,
    short* __restrict__ O2, short* __restrict__ O3)
{
    const float* W = (blockIdx.y == 0) ? W0 : (blockIdx.y == 1) ? W1 : (blockIdx.y == 2) ? W2 : W3;
    short* O = (blockIdx.y == 0) ? O0 : (blockIdx.y == 1) ? O1 : (blockIdx.y == 2) ? O2 : O3;
    int idx = blockIdx.x * 256 + threadIdx.x;   // 0..2047
    int n = idx >> 8, ks = (idx >> 6) & 3, lane = idx & 63;
    int k8 = ks * 32 + (lane >> 4) * 8;
    int col = n * 16 + (lane & 15);
    bf16x8 fv;
    #pragma unroll
    for (int i2 = 0; i2 < 8; i2++) fv[i2] = f2bf(W[(k8 + i2) * 128 + col]);
    *(bf16x8*)(O + (size_t)idx * 8) = fv;
}

// BN-folding repack: B' = diag(s)@W fragments, bias' = bias + t@W (block 0).
// stats: 16 replicas of [sum[128], sumsq[128]]
__global__ __launch_bounds__(256) void fold_k(
    const float* __restrict__ W, const float* __restrict__ bias,
    const float* __restrict__ statsG, const float* __restrict__ gamma,
    const float* __restrict__ beta, float invNs,
    short* __restrict__ Bp, float* __restrict__ biasOut)
{
    __shared__ float sS[128], sT[128];
    int tid = threadIdx.x;
    if (tid < 128) {
        float sum = 0.f, sq = 0.f;
        for (int r = 0; r < 16; r++) {
            sum += statsG[r * 256 + tid];
            sq  += statsG[r * 256 + 128 + tid];
        }
        float m = sum * invNs;
        float var = sq * invNs - m * m;
        float rs = rsqrtf(var + 1e-5f);
        float s = rs * gamma[tid];
        float t = beta[tid] - m * s;
        sS[tid] = s; sT[tid] = t;
    }
    __syncthreads();
    if (blockIdx.x == 0 && tid < 128) {
        float b = bias[tid];
        for (int k = 0; k < 128; k++) b += sT[k] * W[k * 128 + tid];
        biasOut[tid] = b;
    }
    int idx = blockIdx.x * 256 + tid;  // grid 8 -> 0..2047
    int n = idx >> 8, ks = (idx >> 6) & 3, lane = idx & 63;
    int k8 = ks * 32 + (lane >> 4) * 8;
    int col = n * 16 + (lane & 15);
    bf16x8 fv;
    #pragma unroll
    for (int i2 = 0; i2 < 8; i2++)
        fv[i2] = f2bf(sS[k8 + i2] * W[(k8 + i2) * 128 + col]);
    *(bf16x8*)(Bp + (size_t)idx * 8) = fv;
}

// ---------------- fused node precompute: xd/zacc/xs1/xt1 from one read of x ----------------
__global__ __launch_bounds__(256) void node_pre_k(
    const float* __restrict__ x, int M,
    const short* __restrict__ bp3,   // BpWd | BpXs | BpXt contiguous (3 x 16384 shorts)
    const float* __restrict__ bd, const float* __restrict__ vv,
    short* __restrict__ xdb, short* __restrict__ zaccb,
    short* __restrict__ xs1b, short* __restrict__ xt1b)
{
    __shared__ __align__(16) short ldsB[16384];
    int tid = threadIdx.x;
    int wave = tid >> 6, lane = tid & 63;
    int kgrp = lane >> 4, colbase = lane & 15;
    int rowA = blockIdx.x * 64 + wave * 16 + colbase;
    bool rvalid = rowA < M;

    bf16x8 af[4];
    #pragma unroll
    for (int ks = 0; ks < 4; ks++) {
        af[ks] = (bf16x8){0, 0, 0, 0, 0, 0, 0, 0};
        if (rvalid) {
            const float* ap = x + (size_t)rowA * 128 + ks * 32 + kgrp * 8;
            float4 f0 = ((const float4*)ap)[0];
            float4 f1 = ((const float4*)ap)[1];
            af[ks][0] = f2bf(f0.x); af[ks][1] = f2bf(f0.y); af[ks][2] = f2bf(f0.z); af[ks][3] = f2bf(f0.w);
            af[ks][4] = f2bf(f1.x); af[ks][5] = f2bf(f1.y); af[ks][6] = f2bf(f1.z); af[ks][7] = f2bf(f1.w);
        }
    }
    int rbase = blockIdx.x * 64 + wave * 16 + kgrp * 4;

    for (int b = 0; b < 3; b++) {
        {
            const float4* s4 = (const float4*)(bp3 + (size_t)b * 16384);
            float4* d4 = (float4*)ldsB;
            #pragma unroll
            for (int i = 0; i < 8; i++) d4[tid + i * 256] = s4[tid + i * 256];
        }
        __syncthreads();
        f32x4 acc[8];
        #pragma unroll
        for (int n = 0; n < 8; n++) acc[n] = (f32x4){0.f, 0.f, 0.f, 0.f};
        #pragma unroll
        for (int ks = 0; ks < 4; ks++) {
            #pragma unroll
            for (int n = 0; n < 8; n++) {
                bf16x8 bf = *(const bf16x8*)(ldsB + ((size_t)((n * 4 + ks) * 64 + lane)) * 8);
                acc[n] = __builtin_amdgcn_mfma_f32_16x16x32_bf16(af[ks], bf, acc[n], 0, 0, 0);
            }
        }
        short* outp = (b == 0) ? xdb : (b == 1) ? xs1b : xt1b;
        #pragma unroll
        for (int n = 0; n < 8; n++) {
            int col = n * 16 + colbase;
            float bc = (b == 0) ? bd[col] : 0.f;
            float vc = (b == 0) ? vv[col] : 0.f;
            #pragma unroll
            for (int r = 0; r < 4; r++) {
                int row = rbase + r;
                if (row < M) {
                    float val = acc[n][r] + bc;
                    outp[(size_t)row * 128 + col] = f2bf(val);
                    if (b == 0) zaccb[(size_t)row * 128 + col] = f2bf(vc * val);
                }
            }
        }
        __syncthreads();
    }
}

// ---------------- edge pass 1: z1 = lrelu(xs1[src]+xt1[dst]+tab lerps) ----------------
__global__ __launch_bounds__(256) void edge_z1_k(
    const short* __restrict__ xs1b, const short* __restrict__ xt1b,
    const short* __restrict__ tab, const float* __restrict__ ea,
    const int* __restrict__ srcI, const int* __restrict__ dstI,
    short* __restrict__ z1, float* __restrict__ stats, int Etot)
{
    int tid = threadIdx.x;
    int j = tid & 127, hh = tid >> 7;
    int e0 = blockIdx.x * 256;
    float sum = 0.f, sq = 0.f;
    for (int el = hh; el < 256; el += 2) {
        int e = e0 + el;
        if (e < Etot) {
            int s = srcI[e], d = dstI[e];
            float pre = bf2f(xs1b[(size_t)s * 128 + j]) + bf2f(xt1b[(size_t)d * 128 + j]);
            #pragma unroll
            for (int c = 0; c < 4; c++) {
                float t = ea[(size_t)e * 4 + c];
                float u = t * 1024.f;
                int i0 = (int)u;
                if (i0 > 1023) i0 = 1023;
                if (i0 < 0) i0 = 0;
                float f = u - (float)i0;
                const short* tb = tab + ((size_t)(c * 1025 + i0)) * 128 + j;
                float v0 = bf2f(tb[0]), v1 = bf2f(tb[128]);
                pre += v0 + f * (v1 - v0);
            }
            float z = pre >= 0.f ? pre : 0.01f * pre;
            z1[(size_t)e * 128 + j] = f2bf(z);
            sum += z; sq += z * z;
        }
    }
    __shared__ float lS[256], lQ[256];
    lS[tid] = sum; lQ[tid] = sq;
    __syncthreads();
    if (tid < 128) {
        float s2 = lS[tid] + lS[tid + 128];
        float q2 = lQ[tid] + lQ[tid + 128];
        int rep = blockIdx.x & 15;
        atomicAdd(&stats[rep * 256 + tid], s2);
        atomicAdd(&stats[rep * 256 + 128 + tid], q2);
    }
}

// ---------------- tall-skinny MFMA GEMM: out = A(Mx128, bf16) @ B'(128x128) ----------------
// EPI 2: z=lrelu(val); out bf16; BN stats
// EPI 3: scatter: pk_add_bf16(zacc[dst], coeff*val*xd[src])
// EPI 4: out fp32 = val + xres
template<int EPI>
__global__ __launch_bounds__(256) void gemm_k(
    const short* __restrict__ A, int M,
    const short* __restrict__ Bp, const float* __restrict__ bias,
    void* __restrict__ out, float* __restrict__ stats,
    const short* __restrict__ xdb, short* __restrict__ zaccb,
    const float* __restrict__ ea, const int* __restrict__ srcI,
    const int* __restrict__ dstI, const float* __restrict__ xres)
{
    __shared__ __align__(16) short ldsB[16384];
    __shared__ float ldsS[128], ldsQ[128];
    int tid = threadIdx.x;
    {
        const float4* s4 = (const float4*)Bp;
        float4* d4 = (float4*)ldsB;
        #pragma unroll
        for (int i = 0; i < 8; i++) d4[tid + i * 256] = s4[tid + i * 256];
    }
    if (EPI == 2) { if (tid < 128) { ldsS[tid] = 0.f; ldsQ[tid] = 0.f; } }
    __syncthreads();

    int wave = tid >> 6, lane = tid & 63;
    int kgrp = lane >> 4;
    int colbase = lane & 15;
    int rowA = blockIdx.x * 64 + wave * 16 + colbase;
    bool rvalid = rowA < M;

    f32x4 acc[8];
    #pragma unroll
    for (int n = 0; n < 8; n++) acc[n] = (f32x4){0.f, 0.f, 0.f, 0.f};

    #pragma unroll
    for (int ks = 0; ks < 4; ks++) {
        bf16x8 af = (bf16x8){0, 0, 0, 0, 0, 0, 0, 0};
        if (rvalid)
            af = *(const bf16x8*)(A + (size_t)rowA * 128 + ks * 32 + kgrp * 8);
        #pragma unroll
        for (int n = 0; n < 8; n++) {
            bf16x8 bf = *(const bf16x8*)(ldsB + ((size_t)((n * 4 + ks) * 64 + lane)) * 8);
            acc[n] = __builtin_amdgcn_mfma_f32_16x16x32_bf16(af, bf, acc[n], 0, 0, 0);
        }
    }

    int rbase = blockIdx.x * 64 + wave * 16 + kgrp * 4;
    float bcol[8];
    #pragma unroll
    for (int n = 0; n < 8; n++) bcol[n] = bias ? bias[n * 16 + colbase] : 0.f;

    if (EPI == 2) {
        short* outh = (short*)out;
        #pragma unroll
        for (int n = 0; n < 8; n++) {
            int col = n * 16 + colbase;
            float s4 = 0.f, q4 = 0.f;
            #pragma unroll
            for (int r = 0; r < 4; r++) {
                int row = rbase + r;
                if (row < M) {
                    float z = acc[n][r] + bcol[n];
                    z = z >= 0.f ? z : 0.01f * z;
                    outh[(size_t)row * 128 + col] = f2bf(z);
                    s4 += z; q4 += z * z;
                }
            }
            atomicAdd(&ldsS[col], s4);
            atomicAdd(&ldsQ[col], q4);
        }
        __syncthreads();
        if (tid < 128) {
            int rep = blockIdx.x & 15;
            atomicAdd(&stats[rep * 256 + tid], ldsS[tid]);
            atomicAdd(&stats[rep * 256 + 128 + tid], ldsQ[tid]);
        }
    } else if (EPI == 3) {
        int sx4[4], dx4[4]; float cf[4]; bool ok[4];
        #pragma unroll
        for (int r = 0; r < 4; r++) {
            int row = rbase + r;
            ok[r] = row < M;
            if (ok[r]) {
                sx4[r] = srcI[row]; dx4[r] = dstI[row];
                cf[r] = cosf(1.57079632679f * ea[(size_t)row * 4 + 3]);
            } else { sx4[r] = 0; dx4[r] = 0; cf[r] = 0.f; }
        }
        #pragma unroll
        for (int n = 0; n < 8; n++) {
            int col = n * 16 + colbase;
            #pragma unroll
            for (int r = 0; r < 4; r++) {
                float mm = 0.f;
                if (ok[r]) {
                    float val = acc[n][r] + bcol[n];
                    mm = cf[r] * val * bf2f(xdb[(size_t)sx4[r] * 128 + col]);
                }
                float nb = __shfl_xor(mm, 1);
                if (ok[r] && !(lane & 1)) {
                    unsigned packed = (unsigned)(unsigned short)f2bf(mm)
                                    | ((unsigned)(unsigned short)f2bf(nb) << 16);
                    short* ap = zaccb + (size_t)dx4[r] * 128 + col;
                    asm volatile("global_atomic_pk_add_bf16 %0, %1, off"
                                 :: "v"(ap), "v"(packed) : "memory");
                }
            }
        }
    } else if (EPI == 4) {
        float* outf = (float*)out;
        #pragma unroll
        for (int n = 0; n < 8; n++) {
            int col = n * 16 + colbase;
            #pragma unroll
            for (int r = 0; r < 4; r++) {
                int row = rbase + r;
                if (row < M)
                    outf[(size_t)row * 128 + col] = acc[n][r] + bcol[n] + xres[(size_t)row * 128 + col];
            }
        }
    }
}

extern "C" void kernel_launch(void* const* d_in, const int* in_sizes, int n_in,
                              void* d_out, int out_size, void* d_ws, size_t ws_size,
                              hipStream_t stream)
{
    const float* x    = (const float*)d_in[0];
    const float* ea   = (const float*)d_in[1];
    const int*   eidx = (const int*)d_in[2];
    const float* Wb   = (const float*)d_in[3];
    const float* bb   = (const float*)d_in[4];
    const float* We1  = (const float*)d_in[5];
    const float* be1  = (const float*)d_in[6];
    const float* ge1  = (const float*)d_in[7];
    const float* bte1 = (const float*)d_in[8];
    const float* We2  = (const float*)d_in[9];
    const float* be2  = (const float*)d_in[10];
    const float* ge2  = (const float*)d_in[11];
    const float* bte2 = (const float*)d_in[12];
    const float* We3  = (const float*)d_in[13];
    const float* be3  = (const float*)d_in[14];
    const float* Wd   = (const float*)d_in[15];
    const float* bd   = (const float*)d_in[16];
    const float* vv   = (const float*)d_in[17];
    const float* Wn1  = (const float*)d_in[18];
    const float* bn1  = (const float*)d_in[19];
    const float* gn   = (const float*)d_in[20];
    const float* btn  = (const float*)d_in[21];
    const float* Wn2  = (const float*)d_in[22];
    const float* bn2  = (const float*)d_in[23];

    const int NN = in_sizes[0] / 128;   // 50000
    const int EE = in_sizes[1] / 4;     // 300000

    char* ws = (char*)d_ws;
    size_t oEZ   = 0;
    size_t oXD   = oEZ   + (size_t)EE * 128 * 2;
    size_t oXS   = oXD   + (size_t)NN * 128 * 2;
    size_t oXT   = oXS   + (size_t)NN * 128 * 2;
    size_t oZACC = oXT   + (size_t)NN * 128 * 2;
    size_t oZN   = oZACC + (size_t)NN * 128 * 2;
    size_t oTAB  = oZN   + (size_t)NN * 128 * 2;
    size_t oW1P  = oTAB  + (size_t)4 * 1025 * 128 * 2;
    size_t oB1P  = oW1P  + (size_t)200 * 128 * 4;
    size_t oBP   = oB1P  + 512;
    size_t oBIAS = oBP   + (size_t)7 * 32768;
    size_t oST   = oBIAS + (size_t)7 * 512;

    short* eZ    = (short*)(ws + oEZ);
    short* xdb   = (short*)(ws + oXD);
    short* xs1b  = (short*)(ws + oXS);
    short* xt1b  = (short*)(ws + oXT);
    short* zaccb = (short*)(ws + oZACC);
    short* zn    = (short*)(ws + oZN);
    short* tab   = (short*)(ws + oTAB);
    float* W1p   = (float*)(ws + oW1P);
    float* b1p   = (float*)(ws + oB1P);
    short* bp    = (short*)(ws + oBP);
    short* BpWd  = bp + 0 * 16384;   // bp[0..2] contiguous: Wd, Xs, Xt
    short* BpW2  = bp + 3 * 16384;
    short* BpW3  = bp + 4 * 16384;
    short* BpN1  = bp + 5 * 16384;
    short* BpN2  = bp + 6 * 16384;
    short* BpXs  = bp + 1 * 16384;
    short* BpXt  = bp + 2 * 16384;
    float* bo    = (float*)(ws + oBIAS);
    float* b2p   = bo + 0 * 128;
    float* b3p   = bo + 1 * 128;
    float* b2np  = bo + 2 * 128;
    float* st1   = (float*)(ws + oST);
    float* st2   = st1 + 4096;
    float* stN   = st1 + 8192;

    hipMemsetAsync(st1, 0, 3 * 16384, stream);

    build_w1p_k<<<201, 128, 0, stream>>>(Wb, We1, bb, be1, W1p, b1p);
    build_tab_k<<<dim3(1025, 4), 128, 0, stream>>>(W1p, b1p, tab);

    fold_plain_k<<<dim3(8, 4), 256, 0, stream>>>(
        Wd, We1, We1 + 256 * 128, Wn1, BpWd, BpXs, BpXt, BpN1);

    int gN = (NN + 63) / 64;
    int gE = (EE + 63) / 64;

    node_pre_k<<<gN, 256, 0, stream>>>(x, NN, bp, bd, vv, xdb, zaccb, xs1b, xt1b);

    edge_z1_k<<<(EE + 255) / 256, 256, 0, stream>>>(xs1b, xt1b, tab, ea, eidx, eidx + EE,
                                                    eZ, st1, EE);

    fold_k<<<8, 256, 0, stream>>>(We2, be2, st1, ge1, bte1, 1.f / (float)EE, BpW2, b2p);
    gemm_k<2><<<gE, 256, 0, stream>>>(eZ, EE, BpW2, b2p, eZ, st2,
                                      nullptr, nullptr, nullptr, nullptr, nullptr, nullptr);

    fold_k<<<8, 256, 0, stream>>>(We3, be3, st2, ge2, bte2, 1.f / (float)EE, BpW3, b3p);
    gemm_k<3><<<gE, 256, 0, stream>>>(eZ, EE, BpW3, b3p, nullptr, nullptr,
                                      xdb, zaccb, ea, eidx, eidx + EE, nullptr);

    gemm_k<2><<<gN, 256, 0, stream>>>(zaccb, NN, BpN1, bn1, zn, stN,
                                      nullptr, nullptr, nullptr, nullptr, nullptr, nullptr);

    fold_k<<<8, 256, 0, stream>>>(Wn2, bn2, stN, gn, btn, 1.f / (float)NN, BpN2, b2np);
    gemm_k<4><<<gN, 256, 0, stream>>>(zn, NN, BpN2, b2np, d_out, nullptr,
                                      nullptr, nullptr, nullptr, nullptr, nullptr, x);
}

// Round 3
// 566.536 us; speedup vs baseline: 1.1510x; 1.0667x over previous
//
#include <hip/hip_runtime.h>

typedef __attribute__((ext_vector_type(8))) short bf16x8;
typedef __attribute__((ext_vector_type(4))) float f32x4;

#define DEVFN __device__ __forceinline__

DEVFN short f2bf(float f) {
    union { float f; unsigned u; } v; v.f = f;
    unsigned r = (v.u + 0x7FFFu + ((v.u >> 16) & 1u)) >> 16;
    return (short)(unsigned short)r;
}
DEVFN float bf2f(short h) {
    union { unsigned u; float f; } v; v.u = ((unsigned)(unsigned short)h) << 16;
    return v.f;
}
DEVFN float2 bfpair(unsigned u) {
    union { unsigned v; float f; } a, b;
    a.v = u << 16; b.v = u & 0xFFFF0000u;
    float2 r; r.x = a.f; r.y = b.f; return r;
}

// ---------------- prep kernels ----------------

__global__ __launch_bounds__(128) void build_w1p_k(
    const float* __restrict__ Wb, const float* __restrict__ We1,
    const float* __restrict__ bb, const float* __restrict__ be1,
    float* __restrict__ W1p, float* __restrict__ b1p)
{
    int j = threadIdx.x;
    const float* B = We1 + 128 * 128;
    int i = blockIdx.x;
    if (i < 200) {
        float a = 0.f;
        for (int m = 0; m < 128; m++) a += Wb[i * 128 + m] * B[m * 128 + j];
        W1p[i * 128 + j] = a;
    } else {
        float a = be1[j];
        for (int m = 0; m < 128; m++) a += bb[m] * B[m * 128 + j];
        b1p[j] = a;
    }
}

__global__ __launch_bounds__(128) void build_tab_k(
    const float* __restrict__ W1p, const float* __restrict__ b1p,
    short* __restrict__ tab)
{
    int i = blockIdx.x;   // 0..1024
    int c = blockIdx.y;   // 0..3
    int j = threadIdx.x;
    float t = (float)i * (1.0f / 1024.0f);
    float acc = (c == 0) ? b1p[j] : 0.f;
    int kc = (int)(t * 49.f + 0.5f);
    for (int dk = -6; dk <= 6; dk++) {
        int k = kc + dk;
        if (k >= 0 && k < 50) {
            float d = t - (float)k * (1.f / 49.f);
            float g = expf(-1250.f * d * d);
            acc += g * W1p[(c * 50 + k) * 128 + j];
        }
    }
    tab[((size_t)(c * 1025 + i)) * 128 + j] = f2bf(acc);
}

__global__ __launch_bounds__(256) void fold_plain_k(
    const float* __restrict__ W0, const float* __restrict__ W1,
    const float* __restrict__ W2, const float* __restrict__ W3,
    short* __restrict__ O0, short* __restrict__ O1,
    short* __restrict__ O2, short* __restrict__ O3)
{
    const float* W = (blockIdx.y == 0) ? W0 : (blockIdx.y == 1) ? W1 : (blockIdx.y == 2) ? W2 : W3;
    short* O = (blockIdx.y == 0) ? O0 : (blockIdx.y == 1) ? O1 : (blockIdx.y == 2) ? O2 : O3;
    int idx = blockIdx.x * 256 + threadIdx.x;
    int n = idx >> 8, ks = (idx >> 6) & 3, lane = idx & 63;
    int k8 = ks * 32 + (lane >> 4) * 8;
    int col = n * 16 + (lane & 15);
    bf16x8 fv;
    #pragma unroll
    for (int i2 = 0; i2 < 8; i2++) fv[i2] = f2bf(W[(k8 + i2) * 128 + col]);
    *(bf16x8*)(O + (size_t)idx * 8) = fv;
}

__global__ __launch_bounds__(256) void fold_k(
    const float* __restrict__ W, const float* __restrict__ bias,
    const float* __restrict__ statsG, const float* __restrict__ gamma,
    const float* __restrict__ beta, float invNs,
    short* __restrict__ Bp, float* __restrict__ biasOut)
{
    __shared__ float sS[128], sT[128];
    int tid = threadIdx.x;
    if (tid < 128) {
        float sum = 0.f, sq = 0.f;
        for (int r = 0; r < 16; r++) {
            sum += statsG[r * 256 + tid];
            sq  += statsG[r * 256 + 128 + tid];
        }
        float m = sum * invNs;
        float var = sq * invNs - m * m;
        float rs = rsqrtf(var + 1e-5f);
        float s = rs * gamma[tid];
        float t = beta[tid] - m * s;
        sS[tid] = s; sT[tid] = t;
    }
    __syncthreads();
    if (blockIdx.x == 0 && tid < 128) {
        float b = bias[tid];
        for (int k = 0; k < 128; k++) b += sT[k] * W[k * 128 + tid];
        biasOut[tid] = b;
    }
    int idx = blockIdx.x * 256 + tid;
    int n = idx >> 8, ks = (idx >> 6) & 3, lane = idx & 63;
    int k8 = ks * 32 + (lane >> 4) * 8;
    int col = n * 16 + (lane & 15);
    bf16x8 fv;
    #pragma unroll
    for (int i2 = 0; i2 < 8; i2++)
        fv[i2] = f2bf(sS[k8 + i2] * W[(k8 + i2) * 128 + col]);
    *(bf16x8*)(Bp + (size_t)idx * 8) = fv;
}

// ---------------- counting sort by dst ----------------

__global__ __launch_bounds__(256) void hist_k(
    const int* __restrict__ dstI, int* __restrict__ cnt, int E)
{
    int e = blockIdx.x * 256 + threadIdx.x;
    if (e < E) atomicAdd(&cnt[dstI[e]], 1);
}

__global__ __launch_bounds__(256) void scan1_k(
    const int* __restrict__ cnt, int Nn, int* __restrict__ posE, int* __restrict__ bsum)
{
    __shared__ int s[256];
    int t = threadIdx.x, g = blockIdx.x * 256 + t;
    int v = (g < Nn) ? cnt[g] : 0;
    s[t] = v;
    __syncthreads();
    for (int off = 1; off < 256; off <<= 1) {
        int u = (t >= off) ? s[t - off] : 0;
        __syncthreads();
        s[t] += u;
        __syncthreads();
    }
    if (g < Nn) posE[g] = s[t] - v;
    if (t == 255) bsum[blockIdx.x] = s[255];
}

__global__ __launch_bounds__(256) void scan2_k(int* __restrict__ bsum, int nb)
{
    __shared__ int s[256];
    int t = threadIdx.x;
    int v = (t < nb) ? bsum[t] : 0;
    s[t] = v;
    __syncthreads();
    for (int off = 1; off < 256; off <<= 1) {
        int u = (t >= off) ? s[t - off] : 0;
        __syncthreads();
        s[t] += u;
        __syncthreads();
    }
    if (t < nb) bsum[t] = s[t] - v;
}

__global__ __launch_bounds__(256) void fix_k(
    const int* __restrict__ posE, const int* __restrict__ bsum,
    int* __restrict__ pos2, int Nn)
{
    int id = blockIdx.x * 256 + threadIdx.x;
    if (id < Nn) pos2[id] = posE[id] + bsum[id >> 8];
}

__global__ __launch_bounds__(256) void scat_k(
    const int* __restrict__ srcI, const int* __restrict__ dstI,
    const float4* __restrict__ ea4, int* __restrict__ pos2,
    int* __restrict__ sSrc, int* __restrict__ sDst,
    float* __restrict__ scf, float4* __restrict__ sEa, int E)
{
    int e = blockIdx.x * 256 + threadIdx.x;
    if (e >= E) return;
    int d = dstI[e];
    int p = atomicAdd(&pos2[d], 1);
    sSrc[p] = srcI[e];
    sDst[p] = d;
    float4 ev = ea4[e];
    sEa[p] = ev;
    scf[p] = cosf(1.57079632679f * ev.w);
}

// ---------------- fused node precompute ----------------
__global__ __launch_bounds__(256) void node_pre_k(
    const float* __restrict__ x, int M,
    const short* __restrict__ bp3,
    const float* __restrict__ bd, const float* __restrict__ vv,
    short* __restrict__ xdb, short* __restrict__ zaccb,
    short* __restrict__ xs1b, short* __restrict__ xt1b)
{
    __shared__ __align__(16) short ldsB[16384];
    int tid = threadIdx.x;
    int wave = tid >> 6, lane = tid & 63;
    int kgrp = lane >> 4, colbase = lane & 15;
    int rowA = blockIdx.x * 64 + wave * 16 + colbase;
    bool rvalid = rowA < M;

    bf16x8 af[4];
    #pragma unroll
    for (int ks = 0; ks < 4; ks++) {
        af[ks] = (bf16x8){0, 0, 0, 0, 0, 0, 0, 0};
        if (rvalid) {
            const float* ap = x + (size_t)rowA * 128 + ks * 32 + kgrp * 8;
            float4 f0 = ((const float4*)ap)[0];
            float4 f1 = ((const float4*)ap)[1];
            af[ks][0] = f2bf(f0.x); af[ks][1] = f2bf(f0.y); af[ks][2] = f2bf(f0.z); af[ks][3] = f2bf(f0.w);
            af[ks][4] = f2bf(f1.x); af[ks][5] = f2bf(f1.y); af[ks][6] = f2bf(f1.z); af[ks][7] = f2bf(f1.w);
        }
    }
    int rbase = blockIdx.x * 64 + wave * 16 + kgrp * 4;

    for (int b = 0; b < 3; b++) {
        {
            const float4* s4 = (const float4*)(bp3 + (size_t)b * 16384);
            float4* d4 = (float4*)ldsB;
            #pragma unroll
            for (int i = 0; i < 8; i++) d4[tid + i * 256] = s4[tid + i * 256];
        }
        __syncthreads();
        f32x4 acc[8];
        #pragma unroll
        for (int n = 0; n < 8; n++) acc[n] = (f32x4){0.f, 0.f, 0.f, 0.f};
        #pragma unroll
        for (int ks = 0; ks < 4; ks++) {
            #pragma unroll
            for (int n = 0; n < 8; n++) {
                bf16x8 bf = *(const bf16x8*)(ldsB + ((size_t)((n * 4 + ks) * 64 + lane)) * 8);
                acc[n] = __builtin_amdgcn_mfma_f32_16x16x32_bf16(af[ks], bf, acc[n], 0, 0, 0);
            }
        }
        short* outp = (b == 0) ? xdb : (b == 1) ? xs1b : xt1b;
        #pragma unroll
        for (int n = 0; n < 8; n++) {
            int col = n * 16 + colbase;
            float bc = (b == 0) ? bd[col] : 0.f;
            float vc = (b == 0) ? vv[col] : 0.f;
            #pragma unroll
            for (int r = 0; r < 4; r++) {
                int row = rbase + r;
                if (row < M) {
                    float val = acc[n][r] + bc;
                    outp[(size_t)row * 128 + col] = f2bf(val);
                    if (b == 0) zaccb[(size_t)row * 128 + col] = f2bf(vc * val);
                }
            }
        }
        __syncthreads();
    }
}

// ---------------- edge pass 1 (sorted order, 2 cols/lane) ----------------
__global__ __launch_bounds__(256) void edge_z1_k(
    const short* __restrict__ xs1b, const short* __restrict__ xt1b,
    const short* __restrict__ tab,
    const int* __restrict__ sSrc, const int* __restrict__ sDst,
    const float4* __restrict__ sEa,
    short* __restrict__ z1, float* __restrict__ stats, int Etot)
{
    int tid = threadIdx.x, wave = tid >> 6, lane = tid & 63;
    int e0 = blockIdx.x * 256 + wave * 64;
    const unsigned* xs2 = (const unsigned*)xs1b;
    const unsigned* xt2 = (const unsigned*)xt1b;
    const unsigned* tb2 = (const unsigned*)tab;
    unsigned* z2 = (unsigned*)z1;

    int eL = e0 + lane;
    int myS = 0, myD = 0;
    float4 myE = {0.f, 0.f, 0.f, 0.f};
    if (eL < Etot) { myS = sSrc[eL]; myD = sDst[eL]; myE = sEa[eL]; }

    float s0 = 0.f, q0 = 0.f, s1 = 0.f, q1 = 0.f;
    int ni = Etot - e0; if (ni > 64) ni = 64;
    for (int i = 0; i < ni; i++) {
        int s = __shfl(myS, i), d = __shfl(myD, i);
        float tv[4];
        tv[0] = __shfl(myE.x, i); tv[1] = __shfl(myE.y, i);
        tv[2] = __shfl(myE.z, i); tv[3] = __shfl(myE.w, i);
        float2 xs = bfpair(xs2[(size_t)s * 64 + lane]);
        float2 xt = bfpair(xt2[(size_t)d * 64 + lane]);
        float p0 = xs.x + xt.x, p1 = xs.y + xt.y;
        #pragma unroll
        for (int c = 0; c < 4; c++) {
            float u = tv[c] * 1024.f;
            int i0 = (int)u;
            if (i0 > 1023) i0 = 1023;
            if (i0 < 0) i0 = 0;
            float f = u - (float)i0;
            size_t base = (size_t)(c * 1025 + i0) * 64 + lane;
            float2 v0 = bfpair(tb2[base]);
            float2 v1 = bfpair(tb2[base + 64]);
            p0 += v0.x + f * (v1.x - v0.x);
            p1 += v0.y + f * (v1.y - v0.y);
        }
        float z0 = p0 >= 0.f ? p0 : 0.01f * p0;
        float z1v = p1 >= 0.f ? p1 : 0.01f * p1;
        unsigned packed = (unsigned)(unsigned short)f2bf(z0)
                        | ((unsigned)(unsigned short)f2bf(z1v) << 16);
        z2[(size_t)(e0 + i) * 64 + lane] = packed;
        s0 += z0; q0 += z0 * z0; s1 += z1v; q1 += z1v * z1v;
    }

    __shared__ float lS[128], lQ[128];
    if (tid < 128) { lS[tid] = 0.f; lQ[tid] = 0.f; }
    __syncthreads();
    atomicAdd(&lS[2 * lane], s0);     atomicAdd(&lS[2 * lane + 1], s1);
    atomicAdd(&lQ[2 * lane], q0);     atomicAdd(&lQ[2 * lane + 1], q1);
    __syncthreads();
    if (tid < 128) {
        int rep = blockIdx.x & 15;
        atomicAdd(&stats[rep * 256 + tid], lS[tid]);
        atomicAdd(&stats[rep * 256 + 128 + tid], lQ[tid]);
    }
}

// ---------------- tall-skinny MFMA GEMM ----------------
// EPI 2: z=lrelu(val); out bf16; BN stats
// EPI 3: dst-sorted scatter with LDS segment aggregation -> pk_add_bf16
// EPI 4: out fp32 = val + xres
template<int EPI>
__global__ __launch_bounds__(256) void gemm_k(
    const short* __restrict__ A, int M,
    const short* __restrict__ Bp, const float* __restrict__ bias,
    void* __restrict__ out, float* __restrict__ stats,
    const short* __restrict__ xdb, short* __restrict__ zaccb,
    const float* __restrict__ scf, const int* __restrict__ sSrc,
    const int* __restrict__ sDst, const float* __restrict__ xres)
{
    __shared__ __align__(16) short ldsB[16384];
    __shared__ float ldsS[128], ldsQ[128];
    __shared__ int sDstL[64], headDstL[64];
    __shared__ unsigned char slotL[64];
    __shared__ int nslotsL;
    int tid = threadIdx.x;
    {
        const float4* s4 = (const float4*)Bp;
        float4* d4 = (float4*)ldsB;
        #pragma unroll
        for (int i = 0; i < 8; i++) d4[tid + i * 256] = s4[tid + i * 256];
    }
    if (EPI == 2) { if (tid < 128) { ldsS[tid] = 0.f; ldsQ[tid] = 0.f; } }
    if (EPI == 3) {
        if (tid < 64) {
            int row = blockIdx.x * 64 + tid;
            sDstL[tid] = (row < M) ? sDst[row] : -1;
        }
    }
    __syncthreads();
    if (EPI == 3) {
        if (tid < 64) {   // exactly wave 0
            int d = sDstL[tid];
            bool head = (tid == 0) || (d != sDstL[tid - 1]);
            unsigned long long m = __ballot(head);
            unsigned long long mask = (tid == 63) ? ~0ull : ((2ull << tid) - 1);
            int slot = __popcll(m & mask) - 1;
            slotL[tid] = (unsigned char)slot;
            if (head) headDstL[slot] = d;
            if (tid == 63) nslotsL = slot + 1;
        }
    }

    int wave = tid >> 6, lane = tid & 63;
    int kgrp = lane >> 4;
    int colbase = lane & 15;
    int rowA = blockIdx.x * 64 + wave * 16 + colbase;
    bool rvalid = rowA < M;

    f32x4 acc[8];
    #pragma unroll
    for (int n = 0; n < 8; n++) acc[n] = (f32x4){0.f, 0.f, 0.f, 0.f};

    #pragma unroll
    for (int ks = 0; ks < 4; ks++) {
        bf16x8 af = (bf16x8){0, 0, 0, 0, 0, 0, 0, 0};
        if (rvalid)
            af = *(const bf16x8*)(A + (size_t)rowA * 128 + ks * 32 + kgrp * 8);
        #pragma unroll
        for (int n = 0; n < 8; n++) {
            bf16x8 bf = *(const bf16x8*)(ldsB + ((size_t)((n * 4 + ks) * 64 + lane)) * 8);
            acc[n] = __builtin_amdgcn_mfma_f32_16x16x32_bf16(af, bf, acc[n], 0, 0, 0);
        }
    }

    int rbase = blockIdx.x * 64 + wave * 16 + kgrp * 4;
    float bcol[8];
    #pragma unroll
    for (int n = 0; n < 8; n++) bcol[n] = bias ? bias[n * 16 + colbase] : 0.f;

    if (EPI == 2) {
        short* outh = (short*)out;
        #pragma unroll
        for (int n = 0; n < 8; n++) {
            int col = n * 16 + colbase;
            float s4 = 0.f, q4 = 0.f;
            #pragma unroll
            for (int r = 0; r < 4; r++) {
                int row = rbase + r;
                if (row < M) {
                    float z = acc[n][r] + bcol[n];
                    z = z >= 0.f ? z : 0.01f * z;
                    outh[(size_t)row * 128 + col] = f2bf(z);
                    s4 += z; q4 += z * z;
                }
            }
            atomicAdd(&ldsS[col], s4);
            atomicAdd(&ldsQ[col], q4);
        }
        __syncthreads();
        if (tid < 128) {
            int rep = blockIdx.x & 15;
            atomicAdd(&stats[rep * 256 + tid], ldsS[tid]);
            atomicAdd(&stats[rep * 256 + 128 + tid], ldsQ[tid]);
        }
    } else if (EPI == 3) {
        // per-row metadata
        int lrB = wave * 16 + kgrp * 4;
        int sx4[4]; float cf4[4]; int sl4[4]; bool ok4[4];
        #pragma unroll
        for (int r = 0; r < 4; r++) {
            int lr = lrB + r;
            int row = blockIdx.x * 64 + lr;
            ok4[r] = row < M;
            sl4[r] = slotL[lr];   // valid after barrier below? no -- see barrier placement
            if (ok4[r]) { sx4[r] = sSrc[row]; cf4[r] = scf[row]; }
            else        { sx4[r] = 0; cf4[r] = 0.f; }
        }
        __syncthreads();               // MFMA reads of ldsB done; slotL/headDst visible
        #pragma unroll
        for (int r = 0; r < 4; r++) sl4[r] = slotL[lrB + r];
        float* accL = (float*)ldsB;    // 64 x 128 fp32 = 32 KB, overlays B tile
        for (int i = tid; i < 8192; i += 256) accL[i] = 0.f;
        __syncthreads();
        #pragma unroll
        for (int n = 0; n < 8; n++) {
            int col = n * 16 + colbase;
            float run = 0.f; int cur = sl4[0];
            #pragma unroll
            for (int r = 0; r < 4; r++) {
                float mm = 0.f;
                if (ok4[r]) {
                    float val = acc[n][r] + bcol[n];
                    mm = cf4[r] * val * bf2f(xdb[(size_t)sx4[r] * 128 + col]);
                }
                if (sl4[r] != cur) {
                    atomicAdd(&accL[cur * 128 + col], run);
                    run = 0.f; cur = sl4[r];
                }
                run += mm;
            }
            atomicAdd(&accL[cur * 128 + col], run);
        }
        __syncthreads();
        int tot = nslotsL << 6;
        for (int i = tid; i < tot; i += 256) {
            int s = i >> 6, cp = i & 63;
            int d = headDstL[s];
            if (d < 0) continue;
            float a0 = accL[s * 128 + cp * 2];
            float a1 = accL[s * 128 + cp * 2 + 1];
            unsigned packed = (unsigned)(unsigned short)f2bf(a0)
                            | ((unsigned)(unsigned short)f2bf(a1) << 16);
            short* ap = zaccb + (size_t)d * 128 + cp * 2;
            asm volatile("global_atomic_pk_add_bf16 %0, %1, off"
                         :: "v"(ap), "v"(packed) : "memory");
        }
    } else if (EPI == 4) {
        float* outf = (float*)out;
        #pragma unroll
        for (int n = 0; n < 8; n++) {
            int col = n * 16 + colbase;
            #pragma unroll
            for (int r = 0; r < 4; r++) {
                int row = rbase + r;
                if (row < M)
                    outf[(size_t)row * 128 + col] = acc[n][r] + bcol[n] + xres[(size_t)row * 128 + col];
            }
        }
    }
}

extern "C" void kernel_launch(void* const* d_in, const int* in_sizes, int n_in,
                              void* d_out, int out_size, void* d_ws, size_t ws_size,
                              hipStream_t stream)
{
    const float* x    = (const float*)d_in[0];
    const float* ea   = (const float*)d_in[1];
    const int*   eidx = (const int*)d_in[2];
    const float* Wb   = (const float*)d_in[3];
    const float* bb   = (const float*)d_in[4];
    const float* We1  = (const float*)d_in[5];
    const float* be1  = (const float*)d_in[6];
    const float* ge1  = (const float*)d_in[7];
    const float* bte1 = (const float*)d_in[8];
    const float* We2  = (const float*)d_in[9];
    const float* be2  = (const float*)d_in[10];
    const float* ge2  = (const float*)d_in[11];
    const float* bte2 = (const float*)d_in[12];
    const float* We3  = (const float*)d_in[13];
    const float* be3  = (const float*)d_in[14];
    const float* Wd   = (const float*)d_in[15];
    const float* bd   = (const float*)d_in[16];
    const float* vv   = (const float*)d_in[17];
    const float* Wn1  = (const float*)d_in[18];
    const float* bn1  = (const float*)d_in[19];
    const float* gn   = (const float*)d_in[20];
    const float* btn  = (const float*)d_in[21];
    const float* Wn2  = (const float*)d_in[22];
    const float* bn2  = (const float*)d_in[23];

    const int NN = in_sizes[0] / 128;   // 50000
    const int EE = in_sizes[1] / 4;     // 300000

    char* ws = (char*)d_ws;
    size_t oEZ   = 0;
    size_t oXD   = oEZ   + (size_t)EE * 256;
    size_t oXS   = oXD   + (size_t)NN * 256;
    size_t oXT   = oXS   + (size_t)NN * 256;
    size_t oZACC = oXT   + (size_t)NN * 256;
    size_t oZN   = oZACC + (size_t)NN * 256;
    size_t oTAB  = oZN   + (size_t)NN * 256;
    size_t oW1P  = oTAB  + (size_t)4 * 1025 * 256;
    size_t oB1P  = oW1P  + (size_t)200 * 512;
    size_t oBP   = oB1P  + 512;
    size_t oBIAS = oBP   + (size_t)7 * 32768;
    size_t oST   = oBIAS + (size_t)7 * 512;
    size_t oCNT  = oST   + 49152;
    size_t oPOS  = oCNT  + 201728;
    size_t oBSUM = oPOS  + 201728;
    size_t oPOS2 = oBSUM + 1024;
    size_t oSSRC = oPOS2 + 201728;
    size_t oSDST = oSSRC + (size_t)EE * 4;
    size_t oSCF  = oSDST + (size_t)EE * 4;
    size_t oSEA  = (oSCF + (size_t)EE * 4 + 15) & ~(size_t)15;

    short* eZ    = (short*)(ws + oEZ);
    short* xdb   = (short*)(ws + oXD);
    short* xs1b  = (short*)(ws + oXS);
    short* xt1b  = (short*)(ws + oXT);
    short* zaccb = (short*)(ws + oZACC);
    short* zn    = (short*)(ws + oZN);
    short* tab   = (short*)(ws + oTAB);
    float* W1p   = (float*)(ws + oW1P);
    float* b1p   = (float*)(ws + oB1P);
    short* bp    = (short*)(ws + oBP);
    short* BpW2  = bp + 3 * 16384;
    short* BpW3  = bp + 4 * 16384;
    short* BpN1  = bp + 5 * 16384;
    short* BpN2  = bp + 6 * 16384;
    float* bo    = (float*)(ws + oBIAS);
    float* b2p   = bo + 0 * 128;
    float* b3p   = bo + 1 * 128;
    float* b2np  = bo + 2 * 128;
    float* st1   = (float*)(ws + oST);
    float* st2   = st1 + 4096;
    float* stN   = st1 + 8192;
    int*   cnt   = (int*)(ws + oCNT);
    int*   posE  = (int*)(ws + oPOS);
    int*   bsum  = (int*)(ws + oBSUM);
    int*   pos2  = (int*)(ws + oPOS2);
    int*   sSrc  = (int*)(ws + oSSRC);
    int*   sDst  = (int*)(ws + oSDST);
    float* scf   = (float*)(ws + oSCF);
    float4* sEa  = (float4*)(ws + oSEA);

    // zero stats (48KB) + cnt (197KB) in one shot
    hipMemsetAsync(ws + oST, 0, 49152 + 201728, stream);

    build_w1p_k<<<201, 128, 0, stream>>>(Wb, We1, bb, be1, W1p, b1p);
    build_tab_k<<<dim3(1025, 4), 128, 0, stream>>>(W1p, b1p, tab);
    fold_plain_k<<<dim3(8, 4), 256, 0, stream>>>(
        Wd, We1, We1 + 256 * 128, Wn1, bp, bp + 16384, bp + 2 * 16384, BpN1);

    int gN = (NN + 63) / 64;
    int gE = (EE + 63) / 64;
    int nbN = (NN + 255) / 256;
    int nbE = (EE + 255) / 256;

    node_pre_k<<<gN, 256, 0, stream>>>(x, NN, bp, bd, vv, xdb, zaccb, xs1b, xt1b);

    // counting sort by dst
    hist_k<<<nbE, 256, 0, stream>>>(eidx + EE, cnt, EE);
    scan1_k<<<nbN, 256, 0, stream>>>(cnt, NN, posE, bsum);
    scan2_k<<<1, 256, 0, stream>>>(bsum, nbN);
    fix_k<<<nbN, 256, 0, stream>>>(posE, bsum, pos2, NN);
    scat_k<<<nbE, 256, 0, stream>>>(eidx, eidx + EE, (const float4*)ea, pos2,
                                    sSrc, sDst, scf, sEa, EE);

    edge_z1_k<<<nbE, 256, 0, stream>>>(xs1b, xt1b, tab, sSrc, sDst, sEa, eZ, st1, EE);

    fold_k<<<8, 256, 0, stream>>>(We2, be2, st1, ge1, bte1, 1.f / (float)EE, BpW2, b2p);
    gemm_k<2><<<gE, 256, 0, stream>>>(eZ, EE, BpW2, b2p, eZ, st2,
                                      nullptr, nullptr, nullptr, nullptr, nullptr, nullptr);

    fold_k<<<8, 256, 0, stream>>>(We3, be3, st2, ge2, bte2, 1.f / (float)EE, BpW3, b3p);
    gemm_k<3><<<gE, 256, 0, stream>>>(eZ, EE, BpW3, b3p, nullptr, nullptr,
                                      xdb, zaccb, scf, sSrc, sDst, nullptr);

    gemm_k<2><<<gN, 256, 0, stream>>>(zaccb, NN, BpN1, bn1, zn, stN,
                                      nullptr, nullptr, nullptr, nullptr, nullptr, nullptr);

    fold_k<<<8, 256, 0, stream>>>(Wn2, bn2, stN, gn, btn, 1.f / (float)NN, BpN2, b2np);
    gemm_k<4><<<gN, 256, 0, stream>>>(zn, NN, BpN2, b2np, d_out, nullptr,
                                      nullptr, nullptr, nullptr, nullptr, nullptr, x);
}